// Round 5
// baseline (653.301 us; speedup 1.0000x reference)
//
#include <hip/hip_runtime.h>

typedef __bf16 bf16;
typedef __bf16 bf16x8 __attribute__((ext_vector_type(8)));
typedef __bf16 bf16x4 __attribute__((ext_vector_type(4)));
typedef float f32x4 __attribute__((ext_vector_type(4)));

#define MFMA(a, b, c) __builtin_amdgcn_mfma_f32_16x16x32_bf16(a, b, c, 0, 0, 0)

__device__ __forceinline__ void g2l16(void* lds, const void* g) {
  __builtin_amdgcn_global_load_lds(
      (const __attribute__((address_space(1))) void*)g,
      (__attribute__((address_space(3))) void*)lds, 16, 0, 0);
}

// ---------------- fp32 -> bf16 conversion (weights + pe + X inputs) ----------------
// grid 43920: [0,5120) weights, [5120,5520) pe, [5520,43920) query/key/value.
__global__ void cvt_all(
    const float* __restrict__ Wq, const float* __restrict__ Wk, const float* __restrict__ Wv,
    const float* __restrict__ Wo, const float* __restrict__ Wp, const float* __restrict__ pe,
    const float* __restrict__ Xq, const float* __restrict__ Xk, const float* __restrict__ Xv,
    bf16* __restrict__ wqb, bf16* __restrict__ wkb, bf16* __restrict__ wvb,
    bf16* __restrict__ wob, bf16* __restrict__ wpb, bf16* __restrict__ peb,
    bf16* __restrict__ xqb, bf16* __restrict__ xkb, bf16* __restrict__ xvb) {
  int b = blockIdx.x;
  const float* s;
  bf16* d;
  int lb;
  if (b < 5120) {
    int t = b >> 10;
    lb = b & 1023;
    s = (t == 0) ? Wq : (t == 1) ? Wk : (t == 2) ? Wv : (t == 3) ? Wo : Wp;
    d = (t == 0) ? wqb : (t == 1) ? wkb : (t == 2) ? wvb : (t == 3) ? wob : wpb;
  } else if (b < 5520) {
    lb = b - 5120;
    s = pe;
    d = peb;
  } else {
    int bb = b - 5520;
    int t = bb / 12800;   // 0,1,2
    lb = bb - t * 12800;
    s = (t == 0) ? Xq : (t == 1) ? Xk : Xv;
    d = (t == 0) ? xqb : (t == 1) ? xkb : xvb;
  }
  int i = lb * 256 + threadIdx.x;
  f32x4 v = *(const f32x4*)(s + (size_t)i * 4);
  bf16x4 o;
  o[0] = (bf16)v[0]; o[1] = (bf16)v[1]; o[2] = (bf16)v[2]; o[3] = (bf16)v[3];
  *(bf16x4*)(d + (size_t)i * 4) = o;
}

// ---------------- posq/k/v = bf16(pe @ Wp^T + bp + b{q,k,v}) ----------------
__global__ __launch_bounds__(256) void gemm_pos(
    const bf16* __restrict__ peb, const bf16* __restrict__ Wpb,
    const float* __restrict__ bp, const float* __restrict__ bq,
    const float* __restrict__ bk, const float* __restrict__ bv,
    bf16* __restrict__ posq, bf16* __restrict__ posk, bf16* __restrict__ posv) {
  __shared__ bf16 smA[128 * 32];
  __shared__ bf16 smB[128 * 32];
  const int mbase = blockIdx.y * 128;
  const int nbase = blockIdx.x * 128;
  const int tid = threadIdx.x;
  const int lane = tid & 63, w = tid >> 6;
  const int wm = (w >> 1) * 64, wn = (w & 1) * 64;
  const int lrow = lane & 15, kg = lane >> 4;
  const f32x4 fz = {0.f, 0.f, 0.f, 0.f};
  f32x4 acc[4][4];
#pragma unroll
  for (int i = 0; i < 4; ++i)
#pragma unroll
    for (int j = 0; j < 4; ++j) acc[i][j] = fz;

  for (int k0 = 0; k0 < 1024; k0 += 32) {
    __syncthreads();
#pragma unroll
    for (int it = 0; it < 2; ++it) {
      int j = it * 256 + tid;
      int r = j >> 2, cl = j & 3;
      int c = cl ^ ((r >> 1) & 3);
      if (mbase + r < 400)
        g2l16(smA + j * 8, peb + (mbase + r) * 1024 + k0 + c * 8);
      else {
        uint4 zz = make_uint4(0, 0, 0, 0);
        *(uint4*)(smA + j * 8) = zz;
      }
    }
#pragma unroll
    for (int it = 0; it < 2; ++it) {
      int j = it * 256 + tid;
      int r = j >> 2, cl = j & 3;
      int c = cl ^ ((r >> 1) & 3);
      g2l16(smB + j * 8, Wpb + (nbase + r) * 1024 + k0 + c * 8);
    }
    __syncthreads();
    bf16x8 af[4], bfr[4];
#pragma unroll
    for (int mt = 0; mt < 4; ++mt) {
      int r = wm + mt * 16 + lrow;
      int ch = kg ^ ((r >> 1) & 3);
      af[mt] = *(const bf16x8*)(smA + r * 32 + ch * 8);
    }
#pragma unroll
    for (int nt = 0; nt < 4; ++nt) {
      int r = wn + nt * 16 + lrow;
      int ch = kg ^ ((r >> 1) & 3);
      bfr[nt] = *(const bf16x8*)(smB + r * 32 + ch * 8);
    }
#pragma unroll
    for (int nt = 0; nt < 4; ++nt)
#pragma unroll
      for (int mt = 0; mt < 4; ++mt)
        acc[mt][nt] = MFMA(af[mt], bfr[nt], acc[mt][nt]);
  }
#pragma unroll
  for (int mt = 0; mt < 4; ++mt)
#pragma unroll
    for (int rg = 0; rg < 4; ++rg) {
      int m = mbase + wm + mt * 16 + kg * 4 + rg;
      if (m < 400) {
#pragma unroll
        for (int nt = 0; nt < 4; ++nt) {
          int n = nbase + wn + nt * 16 + lrow;
          float base = acc[mt][nt][rg] + bp[n];
          posq[m * 1024 + n] = (bf16)(base + bq[n]);
          posk[m * 1024 + n] = (bf16)(base + bk[n]);
          posv[m * 1024 + n] = (bf16)(base + bv[n]);
        }
      }
    }
}

// ---------------- QKV projection: bf16 X, dual global_load_lds (m97 structure) ----------------
// grid (832, 3): lid = (m>>3)<<6 | n<<3 | (m&7) — XCD co-residency for X strips.
__global__ __launch_bounds__(512, 4) void gemm_qkv(
    const bf16* __restrict__ Xqb, const bf16* __restrict__ Xkb, const bf16* __restrict__ Xvb,
    const bf16* __restrict__ Wqb, const bf16* __restrict__ Wkb, const bf16* __restrict__ Wvb,
    const bf16* __restrict__ posq, const bf16* __restrict__ posk, const bf16* __restrict__ posv,
    bf16* __restrict__ qb, bf16* __restrict__ kbuf, bf16* __restrict__ vt) {
  const int lid = blockIdx.x;
  const int mI = ((lid >> 6) << 3) + (lid & 7);
  const int nI = (lid >> 3) & 7;
  if (mI >= 100) return;
  __shared__ bf16 sm[16384];  // 32 KB: smA [0,8192), smB [8192,16384)
  bf16* smA = sm;
  bf16* smB = sm + 8192;
  const int z = blockIdx.y;
  const bf16* X = (z == 0) ? Xqb : (z == 1) ? Xkb : Xvb;
  const bf16* W = (z == 0) ? Wqb : (z == 1) ? Wkb : Wvb;
  const bf16* posz = (z == 0) ? posq : (z == 1) ? posk : posv;
  const int mbase = mI * 128;
  const int nbase = nI * 128;
  const int tid = threadIdx.x;
  const int lane = tid & 63, w = tid >> 6;     // w < 8
  const int wm = (w >> 1) * 32, wn = (w & 1) * 64;
  const int lrow = lane & 15, kg = lane >> 4;
  const f32x4 fz = {0.f, 0.f, 0.f, 0.f};
  f32x4 acc[2][4];
#pragma unroll
  for (int i = 0; i < 2; ++i)
#pragma unroll
    for (int j = 0; j < 4; ++j) acc[i][j] = fz;

  for (int k0 = 0; k0 < 1024; k0 += 64) {
    __syncthreads();
#pragma unroll
    for (int it = 0; it < 2; ++it) {
      int j = it * 512 + tid;
      int r = j >> 3, cl = j & 7;
      g2l16(smA + j * 8, X + (size_t)(mbase + r) * 1024 + k0 + (cl ^ (r & 7)) * 8);
    }
#pragma unroll
    for (int it = 0; it < 2; ++it) {
      int j = it * 512 + tid;
      int r = j >> 3, cl = j & 7;
      g2l16(smB + j * 8, W + (size_t)(nbase + r) * 1024 + k0 + (cl ^ (r & 7)) * 8);
    }
    __syncthreads();
#pragma unroll
    for (int ks = 0; ks < 2; ++ks) {
      bf16x8 af[2], bfr[4];
#pragma unroll
      for (int mt = 0; mt < 2; ++mt) {
        int r = wm + mt * 16 + lrow;
        af[mt] = *(const bf16x8*)(smA + r * 64 + ((ks * 4 + kg) ^ (r & 7)) * 8);
      }
#pragma unroll
      for (int nt = 0; nt < 4; ++nt) {
        int r = wn + nt * 16 + lrow;
        bfr[nt] = *(const bf16x8*)(smB + r * 64 + ((ks * 4 + kg) ^ (r & 7)) * 8);
      }
#pragma unroll
      for (int nt = 0; nt < 4; ++nt)
#pragma unroll
        for (int mt = 0; mt < 2; ++mt)
          acc[mt][nt] = MFMA(af[mt], bfr[nt], acc[mt][nt]);
    }
  }

  if (z < 2) {
    bf16* dst = (z == 0) ? qb : kbuf;
#pragma unroll
    for (int mt = 0; mt < 2; ++mt)
#pragma unroll
      for (int rg = 0; rg < 4; ++rg) {
        int m = mbase + wm + mt * 16 + kg * 4 + rg;
        int bI = m / 400;
        int s = m - bI * 400;
#pragma unroll
        for (int nt = 0; nt < 4; ++nt) {
          int n = nbase + wn + nt * 16 + lrow;
          float v = acc[mt][nt][rg] + (float)posz[s * 1024 + n];
          int h = n >> 6, d = n & 63;
          dst[((size_t)(bI * 16 + h) * 400 + s) * 64 + d] = (bf16)v;
        }
      }
  } else {
    __syncthreads();
    bf16* T = sm;  // 128 n x 128 m bf16 = 32 KB, chunk-swizzled
#pragma unroll
    for (int nt = 0; nt < 4; ++nt) {
      int n = wn + nt * 16 + lrow;
      int ng = nbase + n;
#pragma unroll
      for (int mt = 0; mt < 2; ++mt) {
        int m0 = wm + mt * 16 + kg * 4;
        bf16x4 v4;
#pragma unroll
        for (int rg = 0; rg < 4; ++rg) {
          int m = mbase + m0 + rg;
          int bI = m / 400;
          int s = m - bI * 400;
          v4[rg] = (bf16)(acc[mt][nt][rg] + (float)posz[s * 1024 + ng]);
        }
        int chk = m0 >> 3;
        int st = chk ^ (n & 15);
        *(bf16x4*)(T + n * 128 + st * 8 + (m0 & 7)) = v4;
      }
    }
    __syncthreads();
#pragma unroll
    for (int p = 0; p < 4; ++p) {
      int n = p * 32 + (tid >> 4);
      int chk = tid & 15;
      bf16x8 row = *(const bf16x8*)(T + n * 128 + (chk ^ (n & 15)) * 8);
      int ng = nbase + n;
      int h = ng >> 6, d = ng & 63;
      int m = mbase + chk * 8;
      int bI = m / 400;
      int s = m - bI * 400;
      *(bf16x8*)(vt + ((size_t)(bI * 16 + h) * 64 + d) * 400 + s) = row;
    }
  }
}

// ---------------- flash attention: 512 threads, 128-row Q tile, KVBLK=64 ----------------
// grid 2048: lid = (bh>>3)<<5 | qt<<3 | (bh&7); 4 q-tiles of one (b,h) share
// K/V on one XCD. Occupancy play: Q in registers, 64-wide K/V tiles,
// V double-buffered. LDS = 40 KB -> 4 blocks/CU at VGPR<=64 (launch_bounds 8).
__global__ __launch_bounds__(512, 8) void attn_kernel(
    const bf16* __restrict__ qg, const bf16* __restrict__ kg_,
    const bf16* __restrict__ vg, const float* __restrict__ mask,
    bf16* __restrict__ ao) {
  const int lid = blockIdx.x;
  const int qt = (lid >> 3) & 3;
  const int bh = ((lid >> 5) << 3) + (lid & 7);
  __shared__ bf16 smK[64 * 64];       // 8 KB
  __shared__ bf16 smV[2][64 * 64];    // 16 KB (V^T: [d][s]), double-buffered
  __shared__ bf16 smP[128 * 64];      // 16 KB
  const int qbase = qt * 128;
  const int tid = threadIdx.x;
  const int lane = tid & 63;
  const int w = tid >> 6;             // w < 8
  const int lrow = lane & 15, kg = lane >> 4;
  const bf16* Qg = qg + bh * 25600;
  const bf16* Kg = kg_ + bh * 25600;
  const bf16* Vg = vg + bh * 25600;

  // Q fragments in registers: wave w owns q-rows qbase + w*16 + lrow.
  bf16x8 aq[2];
  {
    int rq = qbase + w * 16 + lrow;
    const uint4 zz = make_uint4(0, 0, 0, 0);
#pragma unroll
    for (int ks = 0; ks < 2; ++ks) {
      uint4 v = zz;
      if (rq < 400) v = *(const uint4*)(Qg + rq * 64 + (ks * 4 + kg) * 8);
      aq[ks] = *(const bf16x8*)&v;
    }
  }

  const f32x4 fz = {0.f, 0.f, 0.f, 0.f};
  f32x4 o[4];
#pragma unroll
  for (int i = 0; i < 4; ++i) o[i] = fz;
  float m_run[4], l_part[4];
  int moff[4];
#pragma unroll
  for (int i = 0; i < 4; ++i) {
    m_run[i] = -1e30f;
    l_part[i] = 0.f;
    int qs = qbase + w * 16 + kg * 4 + i;
    moff[i] = ((qs < 400) ? qs : 399) * 400;
  }
  const int stg_r = tid >> 3, stg_c = (tid & 7) ^ (stg_r & 7);  // K/V staging

  // ---- main k-tiles: kt = 0..5 (rows kt*64..kt*64+63 < 384 < 400) ----
  for (int kt = 0; kt < 6; ++kt) {
    bf16* Vb = smV[kt & 1];
    // stage K[kt] (64x64) and V^T[kt] (64x64): one uint4 chunk per thread each
    *(uint4*)(smK + tid * 8) =
        *(const uint4*)(Kg + (kt * 64 + stg_r) * 64 + stg_c * 8);
    *(uint4*)(Vb + tid * 8) =
        *(const uint4*)(Vg + stg_r * 400 + kt * 64 + stg_c * 8);
    __syncthreads();

    f32x4 sc[4];
#pragma unroll
    for (int nt = 0; nt < 4; ++nt) sc[nt] = fz;
    __builtin_amdgcn_s_setprio(1);
#pragma unroll
    for (int ks = 0; ks < 2; ++ks)
#pragma unroll
      for (int nt = 0; nt < 4; ++nt) {
        int rk = nt * 16 + lrow;
        bf16x8 bk8 = *(const bf16x8*)(smK + rk * 64 + (((ks * 4 + kg) ^ (rk & 7)) * 8));
        sc[nt] = MFMA(aq[ks], bk8, sc[nt]);
      }
    __builtin_amdgcn_s_setprio(0);

#pragma unroll
    for (int rg = 0; rg < 4; ++rg) {
      const float* mrow = mask + moff[rg];
      float rmax = -1e30f;
#pragma unroll
      for (int nt = 0; nt < 4; ++nt) {
        int ksi = kt * 64 + nt * 16 + lrow;
        float v = fmaf(sc[nt][rg], 0.125f, mrow[ksi]);
        sc[nt][rg] = v;
        rmax = fmaxf(rmax, v);
      }
#pragma unroll
      for (int off = 1; off < 16; off <<= 1)
        rmax = fmaxf(rmax, __shfl_xor(rmax, off, 64));
      float mn = fmaxf(m_run[rg], rmax);
      float alpha = __expf(m_run[rg] - mn);
      m_run[rg] = mn;
      float rsum = 0.f;
#pragma unroll
      for (int nt = 0; nt < 4; ++nt) {
        float p = __expf(sc[nt][rg] - mn);
        sc[nt][rg] = p;
        rsum += p;
      }
      l_part[rg] = l_part[rg] * alpha + rsum;   // lane-local; reduced at end
      o[0][rg] *= alpha; o[1][rg] *= alpha; o[2][rg] *= alpha; o[3][rg] *= alpha;
    }
#pragma unroll
    for (int nt = 0; nt < 4; ++nt)
#pragma unroll
      for (int rg = 0; rg < 4; ++rg) {
        int row = w * 16 + kg * 4 + rg;
        int col = nt * 16 + lrow;
        int ch = (col >> 3) ^ (row & 7);
        smP[row * 64 + ch * 8 + (col & 7)] = (bf16)sc[nt][rg];
      }
    __syncthreads();
    __builtin_amdgcn_s_setprio(1);
#pragma unroll
    for (int ks2 = 0; ks2 < 2; ++ks2) {
      int rp = w * 16 + lrow;
      bf16x8 ap = *(const bf16x8*)(smP + rp * 64 + (((ks2 * 4 + kg) ^ (rp & 7)) * 8));
#pragma unroll
      for (int nt2 = 0; nt2 < 4; ++nt2) {
        int rv = nt2 * 16 + lrow;
        bf16x8 bv8 = *(const bf16x8*)(Vb + rv * 64 + (((ks2 * 4 + kg) ^ (rv & 7)) * 8));
        o[nt2] = MFMA(ap, bv8, o[nt2]);
      }
    }
    __builtin_amdgcn_s_setprio(0);
    // no barrier here: next stage writes smK / smV[other]; PV reads smP / smV[this].
    // smP is protected by the stage->sync of the next iteration.
  }

  // ---- tail k-tile: k = 384..399 (16 wide), buf = 0 (tile 6) ----
  {
    bf16* Vb = smV[0];
    __syncthreads();  // all waves done with smK(5)/smV[1](5); smV[0] dead since kt=4
    if (tid < 128) {
      int r = tid >> 3, cl = tid & 7;
      *(uint4*)(smK + tid * 8) =
          *(const uint4*)(Kg + (384 + r) * 64 + (cl ^ (r & 7)) * 8);
    } else if (tid < 256) {
      int t2 = tid - 128;
      int r = t2 >> 1, ci = t2 & 1;
      *(uint4*)(Vb + r * 64 + ((ci ^ (r & 7)) * 8)) =
          *(const uint4*)(Vg + r * 400 + 384 + ci * 8);
    }
    __syncthreads();

    f32x4 sc0 = fz;
    __builtin_amdgcn_s_setprio(1);
#pragma unroll
    for (int ks = 0; ks < 2; ++ks) {
      bf16x8 bk8 = *(const bf16x8*)(smK + lrow * 64 + (((ks * 4 + kg) ^ (lrow & 7)) * 8));
      sc0 = MFMA(aq[ks], bk8, sc0);
    }
    __builtin_amdgcn_s_setprio(0);

#pragma unroll
    for (int rg = 0; rg < 4; ++rg) {
      float v = fmaf(sc0[rg], 0.125f, mask[moff[rg] + 384 + lrow]);
      float rmax = v;
#pragma unroll
      for (int off = 1; off < 16; off <<= 1)
        rmax = fmaxf(rmax, __shfl_xor(rmax, off, 64));
      float mn = fmaxf(m_run[rg], rmax);
      float alpha = __expf(m_run[rg] - mn);
      m_run[rg] = mn;
      float p = __expf(v - mn);
      sc0[rg] = p;
      l_part[rg] = l_part[rg] * alpha + p;
      o[0][rg] *= alpha; o[1][rg] *= alpha; o[2][rg] *= alpha; o[3][rg] *= alpha;
    }
    // P cols 0..15 = values, cols 16..31 = 0 (V chunks 2,3 are stale-but-finite x 0)
#pragma unroll
    for (int rg = 0; rg < 4; ++rg) {
      int row = w * 16 + kg * 4 + rg;
      int ch0 = (lrow >> 3) ^ (row & 7);
      smP[row * 64 + ch0 * 8 + (lrow & 7)] = (bf16)sc0[rg];
      int ch1 = (2 + (lrow >> 3)) ^ (row & 7);
      smP[row * 64 + ch1 * 8 + (lrow & 7)] = (bf16)0.f;
    }
    __syncthreads();
    __builtin_amdgcn_s_setprio(1);
    {
      int rp = w * 16 + lrow;
      bf16x8 ap = *(const bf16x8*)(smP + rp * 64 + ((kg ^ (rp & 7)) * 8));
#pragma unroll
      for (int nt2 = 0; nt2 < 4; ++nt2) {
        int rv = nt2 * 16 + lrow;
        bf16x8 bv8 = *(const bf16x8*)(Vb + rv * 64 + ((kg ^ (rv & 7)) * 8));
        o[nt2] = MFMA(ap, bv8, o[nt2]);
      }
    }
    __builtin_amdgcn_s_setprio(0);
  }

  const int b = bh >> 4, h = bh & 15;
#pragma unroll
  for (int rg = 0; rg < 4; ++rg) {
    float l = l_part[rg];
#pragma unroll
    for (int off = 1; off < 16; off <<= 1)
      l += __shfl_xor(l, off, 64);
    int qs = qbase + w * 16 + kg * 4 + rg;
    if (qs < 400) {
      float inv = 1.f / l;
#pragma unroll
      for (int nt2 = 0; nt2 < 4; ++nt2) {
        ao[(b * 400 + qs) * 1024 + h * 64 + nt2 * 16 + lrow] =
            (bf16)(o[nt2][rg] * inv);
      }
    }
  }
}

// ---------------- output projection: 512 threads, BK=64, XCD-swizzled ----------------
__global__ __launch_bounds__(512, 4) void gemm_out(
    const bf16* __restrict__ aop, const bf16* __restrict__ Wob,
    const float* __restrict__ bo, const float* __restrict__ gates,
    float* __restrict__ out) {
  const int lid = blockIdx.x;
  const int mI = ((lid >> 6) << 3) + (lid & 7);
  const int nI = (lid >> 3) & 7;
  if (mI >= 100) return;
  __shared__ bf16 sm[16384];
  bf16* smA = sm;
  bf16* smB = sm + 8192;
  const int mbase = mI * 128;
  const int nbase = nI * 128;
  const int tid = threadIdx.x;
  const int lane = tid & 63, w = tid >> 6;
  const int wm = (w >> 1) * 32, wn = (w & 1) * 64;
  const int lrow = lane & 15, kg = lane >> 4;
  const float g = gates[0];
  const f32x4 fz = {0.f, 0.f, 0.f, 0.f};
  f32x4 acc[2][4];
#pragma unroll
  for (int i = 0; i < 2; ++i)
#pragma unroll
    for (int j = 0; j < 4; ++j) acc[i][j] = fz;

  for (int k0 = 0; k0 < 1024; k0 += 64) {
    __syncthreads();
#pragma unroll
    for (int it = 0; it < 2; ++it) {
      int j = it * 512 + tid;
      int r = j >> 3, cl = j & 7;
      g2l16(smA + j * 8, aop + (size_t)(mbase + r) * 1024 + k0 + (cl ^ (r & 7)) * 8);
    }
#pragma unroll
    for (int it = 0; it < 2; ++it) {
      int j = it * 512 + tid;
      int r = j >> 3, cl = j & 7;
      g2l16(smB + j * 8, Wob + (size_t)(nbase + r) * 1024 + k0 + (cl ^ (r & 7)) * 8);
    }
    __syncthreads();
#pragma unroll
    for (int ks = 0; ks < 2; ++ks) {
      bf16x8 af[2], bfr[4];
#pragma unroll
      for (int mt = 0; mt < 2; ++mt) {
        int r = wm + mt * 16 + lrow;
        af[mt] = *(const bf16x8*)(smA + r * 64 + ((ks * 4 + kg) ^ (r & 7)) * 8);
      }
#pragma unroll
      for (int nt = 0; nt < 4; ++nt) {
        int r = wn + nt * 16 + lrow;
        bfr[nt] = *(const bf16x8*)(smB + r * 64 + ((ks * 4 + kg) ^ (r & 7)) * 8);
      }
#pragma unroll
      for (int nt = 0; nt < 4; ++nt)
#pragma unroll
        for (int mt = 0; mt < 2; ++mt)
          acc[mt][nt] = MFMA(af[mt], bfr[nt], acc[mt][nt]);
    }
  }
#pragma unroll
  for (int mt = 0; mt < 2; ++mt)
#pragma unroll
    for (int rg = 0; rg < 4; ++rg) {
      int m = mbase + wm + mt * 16 + kg * 4 + rg;
#pragma unroll
      for (int nt = 0; nt < 4; ++nt) {
        int n = nbase + wn + nt * 16 + lrow;
        out[(size_t)m * 1024 + n] = (acc[mt][nt][rg] + bo[n]) * g;
      }
    }
}

extern "C" void kernel_launch(void* const* d_in, const int* in_sizes, int n_in,
                              void* d_out, int out_size, void* d_ws, size_t ws_size,
                              hipStream_t stream) {
  const float* query = (const float*)d_in[0];
  const float* key   = (const float*)d_in[1];
  const float* value = (const float*)d_in[2];
  const float* mask  = (const float*)d_in[3];
  const float* pe    = (const float*)d_in[4];
  const float* Wq = (const float*)d_in[5];
  const float* bq = (const float*)d_in[6];
  const float* Wk = (const float*)d_in[7];
  const float* bk = (const float*)d_in[8];
  const float* Wv = (const float*)d_in[9];
  const float* bv = (const float*)d_in[10];
  const float* Wp = (const float*)d_in[11];
  const float* bp = (const float*)d_in[12];
  const float* Wo = (const float*)d_in[13];
  const float* bo = (const float*)d_in[14];
  const float* gates = (const float*)d_in[15];
  float* out = (float*)d_out;

  char* base = (char*)d_ws;
  size_t off = 0;
  bf16* wq_b = (bf16*)(base + off); off += 2097152;
  bf16* wk_b = (bf16*)(base + off); off += 2097152;
  bf16* wv_b = (bf16*)(base + off); off += 2097152;
  bf16* wo_b = (bf16*)(base + off); off += 2097152;
  bf16* wp_b = (bf16*)(base + off); off += 2097152;
  bf16* pe_b = (bf16*)(base + off); off += 819200;
  bf16* posq = (bf16*)(base + off); off += 819200;
  bf16* posk = (bf16*)(base + off); off += 819200;
  bf16* posv = (bf16*)(base + off); off += 819200;
  bf16* qb = (bf16*)(base + off); off += 26214400;
  bf16* kb = (bf16*)(base + off); off += 26214400;
  bf16* vt = (bf16*)(base + off); off += 26214400;
  bf16* ao = (bf16*)(base + off); off += 26214400;
  // bf16 X buffers: xq aliases ao (ao written only by attn, after gemm_qkv is
  // done reading xq). xk/xv live in d_out scratch (52.4 MB, fully overwritten
  // by gemm_out at the end — nothing reads stale d_out contents).
  bf16* xq_b = ao;
  bf16* xk_b = (bf16*)d_out;
  bf16* xv_b = (bf16*)d_out + 13107200;
  (void)ws_size; (void)in_sizes; (void)n_in; (void)out_size;

  cvt_all<<<43920, 256, 0, stream>>>(Wq, Wk, Wv, Wo, Wp, pe,
                                     query, key, value,
                                     wq_b, wk_b, wv_b, wo_b, wp_b, pe_b,
                                     xq_b, xk_b, xv_b);
  gemm_pos<<<dim3(8, 4), 256, 0, stream>>>(pe_b, wp_b, bp, bq, bk, bv,
                                           posq, posk, posv);
  gemm_qkv<<<dim3(832, 3), 512, 0, stream>>>(xq_b, xk_b, xv_b,
                                             wq_b, wk_b, wv_b,
                                             posq, posk, posv, qb, kb, vt);
  attn_kernel<<<2048, 512, 0, stream>>>(qb, kb, vt, mask, ao);
  gemm_out<<<832, 512, 0, stream>>>(ao, wo_b, bo, gates, out);
}

// Round 6
// 446.893 us; speedup vs baseline: 1.4619x; 1.4619x over previous
//
#include <hip/hip_runtime.h>

typedef __bf16 bf16;
typedef __bf16 bf16x8 __attribute__((ext_vector_type(8)));
typedef __bf16 bf16x4 __attribute__((ext_vector_type(4)));
typedef float f32x4 __attribute__((ext_vector_type(4)));

#define MFMA(a, b, c) __builtin_amdgcn_mfma_f32_16x16x32_bf16(a, b, c, 0, 0, 0)

__device__ __forceinline__ void g2l16(void* lds, const void* g) {
  __builtin_amdgcn_global_load_lds(
      (const __attribute__((address_space(1))) void*)g,
      (__attribute__((address_space(3))) void*)lds, 16, 0, 0);
}

// ---------------- fp32 -> bf16 conversion (weights + pe + X inputs) ----------------
// grid 43920: [0,5120) weights, [5120,5520) pe, [5520,43920) query/key/value.
__global__ void cvt_all(
    const float* __restrict__ Wq, const float* __restrict__ Wk, const float* __restrict__ Wv,
    const float* __restrict__ Wo, const float* __restrict__ Wp, const float* __restrict__ pe,
    const float* __restrict__ Xq, const float* __restrict__ Xk, const float* __restrict__ Xv,
    bf16* __restrict__ wqb, bf16* __restrict__ wkb, bf16* __restrict__ wvb,
    bf16* __restrict__ wob, bf16* __restrict__ wpb, bf16* __restrict__ peb,
    bf16* __restrict__ xqb, bf16* __restrict__ xkb, bf16* __restrict__ xvb) {
  int b = blockIdx.x;
  const float* s;
  bf16* d;
  int lb;
  if (b < 5120) {
    int t = b >> 10;
    lb = b & 1023;
    s = (t == 0) ? Wq : (t == 1) ? Wk : (t == 2) ? Wv : (t == 3) ? Wo : Wp;
    d = (t == 0) ? wqb : (t == 1) ? wkb : (t == 2) ? wvb : (t == 3) ? wob : wpb;
  } else if (b < 5520) {
    lb = b - 5120;
    s = pe;
    d = peb;
  } else {
    int bb = b - 5520;
    int t = bb / 12800;   // 0,1,2
    lb = bb - t * 12800;
    s = (t == 0) ? Xq : (t == 1) ? Xk : Xv;
    d = (t == 0) ? xqb : (t == 1) ? xkb : xvb;
  }
  int i = lb * 256 + threadIdx.x;
  f32x4 v = *(const f32x4*)(s + (size_t)i * 4);
  bf16x4 o;
  o[0] = (bf16)v[0]; o[1] = (bf16)v[1]; o[2] = (bf16)v[2]; o[3] = (bf16)v[3];
  *(bf16x4*)(d + (size_t)i * 4) = o;
}

// ---------------- posq/k/v = bf16(pe @ Wp^T + bp + b{q,k,v}) ----------------
__global__ __launch_bounds__(256) void gemm_pos(
    const bf16* __restrict__ peb, const bf16* __restrict__ Wpb,
    const float* __restrict__ bp, const float* __restrict__ bq,
    const float* __restrict__ bk, const float* __restrict__ bv,
    bf16* __restrict__ posq, bf16* __restrict__ posk, bf16* __restrict__ posv) {
  __shared__ bf16 smA[128 * 32];
  __shared__ bf16 smB[128 * 32];
  const int mbase = blockIdx.y * 128;
  const int nbase = blockIdx.x * 128;
  const int tid = threadIdx.x;
  const int lane = tid & 63, w = tid >> 6;
  const int wm = (w >> 1) * 64, wn = (w & 1) * 64;
  const int lrow = lane & 15, kg = lane >> 4;
  const f32x4 fz = {0.f, 0.f, 0.f, 0.f};
  f32x4 acc[4][4];
#pragma unroll
  for (int i = 0; i < 4; ++i)
#pragma unroll
    for (int j = 0; j < 4; ++j) acc[i][j] = fz;

  for (int k0 = 0; k0 < 1024; k0 += 32) {
    __syncthreads();
#pragma unroll
    for (int it = 0; it < 2; ++it) {
      int j = it * 256 + tid;
      int r = j >> 2, cl = j & 3;
      int c = cl ^ ((r >> 1) & 3);
      if (mbase + r < 400)
        g2l16(smA + j * 8, peb + (mbase + r) * 1024 + k0 + c * 8);
      else {
        uint4 zz = make_uint4(0, 0, 0, 0);
        *(uint4*)(smA + j * 8) = zz;
      }
    }
#pragma unroll
    for (int it = 0; it < 2; ++it) {
      int j = it * 256 + tid;
      int r = j >> 2, cl = j & 3;
      int c = cl ^ ((r >> 1) & 3);
      g2l16(smB + j * 8, Wpb + (nbase + r) * 1024 + k0 + c * 8);
    }
    __syncthreads();
    bf16x8 af[4], bfr[4];
#pragma unroll
    for (int mt = 0; mt < 4; ++mt) {
      int r = wm + mt * 16 + lrow;
      int ch = kg ^ ((r >> 1) & 3);
      af[mt] = *(const bf16x8*)(smA + r * 32 + ch * 8);
    }
#pragma unroll
    for (int nt = 0; nt < 4; ++nt) {
      int r = wn + nt * 16 + lrow;
      int ch = kg ^ ((r >> 1) & 3);
      bfr[nt] = *(const bf16x8*)(smB + r * 32 + ch * 8);
    }
#pragma unroll
    for (int nt = 0; nt < 4; ++nt)
#pragma unroll
      for (int mt = 0; mt < 4; ++mt)
        acc[mt][nt] = MFMA(af[mt], bfr[nt], acc[mt][nt]);
  }
#pragma unroll
  for (int mt = 0; mt < 4; ++mt)
#pragma unroll
    for (int rg = 0; rg < 4; ++rg) {
      int m = mbase + wm + mt * 16 + kg * 4 + rg;
      if (m < 400) {
#pragma unroll
        for (int nt = 0; nt < 4; ++nt) {
          int n = nbase + wn + nt * 16 + lrow;
          float base = acc[mt][nt][rg] + bp[n];
          posq[m * 1024 + n] = (bf16)(base + bq[n]);
          posk[m * 1024 + n] = (bf16)(base + bk[n]);
          posv[m * 1024 + n] = (bf16)(base + bv[n]);
        }
      }
    }
}

// ---------------- QKV projection: bf16 X, dual global_load_lds (m97 structure) ----------------
// grid (832, 3): lid = (m>>3)<<6 | n<<3 | (m&7) — XCD co-residency for X strips.
__global__ __launch_bounds__(512, 4) void gemm_qkv(
    const bf16* __restrict__ Xqb, const bf16* __restrict__ Xkb, const bf16* __restrict__ Xvb,
    const bf16* __restrict__ Wqb, const bf16* __restrict__ Wkb, const bf16* __restrict__ Wvb,
    const bf16* __restrict__ posq, const bf16* __restrict__ posk, const bf16* __restrict__ posv,
    bf16* __restrict__ qb, bf16* __restrict__ kbuf, bf16* __restrict__ vt) {
  const int lid = blockIdx.x;
  const int mI = ((lid >> 6) << 3) + (lid & 7);
  const int nI = (lid >> 3) & 7;
  if (mI >= 100) return;
  __shared__ bf16 sm[16384];  // 32 KB: smA [0,8192), smB [8192,16384)
  bf16* smA = sm;
  bf16* smB = sm + 8192;
  const int z = blockIdx.y;
  const bf16* X = (z == 0) ? Xqb : (z == 1) ? Xkb : Xvb;
  const bf16* W = (z == 0) ? Wqb : (z == 1) ? Wkb : Wvb;
  const bf16* posz = (z == 0) ? posq : (z == 1) ? posk : posv;
  const int mbase = mI * 128;
  const int nbase = nI * 128;
  const int tid = threadIdx.x;
  const int lane = tid & 63, w = tid >> 6;     // w < 8
  const int wm = (w >> 1) * 32, wn = (w & 1) * 64;
  const int lrow = lane & 15, kg = lane >> 4;
  const f32x4 fz = {0.f, 0.f, 0.f, 0.f};
  f32x4 acc[2][4];
#pragma unroll
  for (int i = 0; i < 2; ++i)
#pragma unroll
    for (int j = 0; j < 4; ++j) acc[i][j] = fz;

  for (int k0 = 0; k0 < 1024; k0 += 64) {
    __syncthreads();
#pragma unroll
    for (int it = 0; it < 2; ++it) {
      int j = it * 512 + tid;
      int r = j >> 3, cl = j & 7;
      g2l16(smA + j * 8, X + (size_t)(mbase + r) * 1024 + k0 + (cl ^ (r & 7)) * 8);
    }
#pragma unroll
    for (int it = 0; it < 2; ++it) {
      int j = it * 512 + tid;
      int r = j >> 3, cl = j & 7;
      g2l16(smB + j * 8, W + (size_t)(nbase + r) * 1024 + k0 + (cl ^ (r & 7)) * 8);
    }
    __syncthreads();
#pragma unroll
    for (int ks = 0; ks < 2; ++ks) {
      bf16x8 af[2], bfr[4];
#pragma unroll
      for (int mt = 0; mt < 2; ++mt) {
        int r = wm + mt * 16 + lrow;
        af[mt] = *(const bf16x8*)(smA + r * 64 + ((ks * 4 + kg) ^ (r & 7)) * 8);
      }
#pragma unroll
      for (int nt = 0; nt < 4; ++nt) {
        int r = wn + nt * 16 + lrow;
        bfr[nt] = *(const bf16x8*)(smB + r * 64 + ((ks * 4 + kg) ^ (r & 7)) * 8);
      }
#pragma unroll
      for (int nt = 0; nt < 4; ++nt)
#pragma unroll
        for (int mt = 0; mt < 2; ++mt)
          acc[mt][nt] = MFMA(af[mt], bfr[nt], acc[mt][nt]);
    }
  }

  if (z < 2) {
    bf16* dst = (z == 0) ? qb : kbuf;
#pragma unroll
    for (int mt = 0; mt < 2; ++mt)
#pragma unroll
      for (int rg = 0; rg < 4; ++rg) {
        int m = mbase + wm + mt * 16 + kg * 4 + rg;
        int bI = m / 400;
        int s = m - bI * 400;
#pragma unroll
        for (int nt = 0; nt < 4; ++nt) {
          int n = nbase + wn + nt * 16 + lrow;
          float v = acc[mt][nt][rg] + (float)posz[s * 1024 + n];
          int h = n >> 6, d = n & 63;
          dst[((size_t)(bI * 16 + h) * 400 + s) * 64 + d] = (bf16)v;
        }
      }
  } else {
    __syncthreads();
    bf16* T = sm;  // 128 n x 128 m bf16 = 32 KB, chunk-swizzled
#pragma unroll
    for (int nt = 0; nt < 4; ++nt) {
      int n = wn + nt * 16 + lrow;
      int ng = nbase + n;
#pragma unroll
      for (int mt = 0; mt < 2; ++mt) {
        int m0 = wm + mt * 16 + kg * 4;
        bf16x4 v4;
#pragma unroll
        for (int rg = 0; rg < 4; ++rg) {
          int m = mbase + m0 + rg;
          int bI = m / 400;
          int s = m - bI * 400;
          v4[rg] = (bf16)(acc[mt][nt][rg] + (float)posz[s * 1024 + ng]);
        }
        int chk = m0 >> 3;
        int st = chk ^ (n & 15);
        *(bf16x4*)(T + n * 128 + st * 8 + (m0 & 7)) = v4;
      }
    }
    __syncthreads();
#pragma unroll
    for (int p = 0; p < 4; ++p) {
      int n = p * 32 + (tid >> 4);
      int chk = tid & 15;
      bf16x8 row = *(const bf16x8*)(T + n * 128 + (chk ^ (n & 15)) * 8);
      int ng = nbase + n;
      int h = ng >> 6, d = ng & 63;
      int m = mbase + chk * 8;
      int bI = m / 400;
      int s = m - bI * 400;
      *(bf16x8*)(vt + ((size_t)(bI * 16 + h) * 64 + d) * 400 + s) = row;
    }
  }
}

// ---------------- flash attention: 512 threads, 128-row Q tile, KVBLK=64 ----------------
// grid 2048: lid = (bh>>3)<<5 | qt<<3 | (bh&7); 4 q-tiles of one (b,h) share
// K/V on one XCD. Q in registers, 64-wide K/V tiles, V double-buffered.
// LDS = 40 KB. launch_bounds (512,4): VGPR cap 128 — allocator free to pick
// the 64-reg tier (4 blocks/CU); the (512,8)=32-reg pin spilled 1.1 GB (r5).
__global__ __launch_bounds__(512, 4) void attn_kernel(
    const bf16* __restrict__ qg, const bf16* __restrict__ kg_,
    const bf16* __restrict__ vg, const float* __restrict__ mask,
    bf16* __restrict__ ao) {
  const int lid = blockIdx.x;
  const int qt = (lid >> 3) & 3;
  const int bh = ((lid >> 5) << 3) + (lid & 7);
  __shared__ bf16 smK[64 * 64];       // 8 KB
  __shared__ bf16 smV[2][64 * 64];    // 16 KB (V^T: [d][s]), double-buffered
  __shared__ bf16 smP[128 * 64];      // 16 KB
  const int qbase = qt * 128;
  const int tid = threadIdx.x;
  const int lane = tid & 63;
  const int w = tid >> 6;             // w < 8
  const int lrow = lane & 15, kg = lane >> 4;
  const bf16* Qg = qg + bh * 25600;
  const bf16* Kg = kg_ + bh * 25600;
  const bf16* Vg = vg + bh * 25600;

  // Q fragments in registers: wave w owns q-rows qbase + w*16 + lrow.
  bf16x8 aq[2];
  {
    int rq = qbase + w * 16 + lrow;
    const uint4 zz = make_uint4(0, 0, 0, 0);
#pragma unroll
    for (int ks = 0; ks < 2; ++ks) {
      uint4 v = zz;
      if (rq < 400) v = *(const uint4*)(Qg + rq * 64 + (ks * 4 + kg) * 8);
      aq[ks] = *(const bf16x8*)&v;
    }
  }

  const f32x4 fz = {0.f, 0.f, 0.f, 0.f};
  f32x4 o[4];
#pragma unroll
  for (int i = 0; i < 4; ++i) o[i] = fz;
  float m_run[4], l_part[4];
  int moff[4];
#pragma unroll
  for (int i = 0; i < 4; ++i) {
    m_run[i] = -1e30f;
    l_part[i] = 0.f;
    int qs = qbase + w * 16 + kg * 4 + i;
    moff[i] = ((qs < 400) ? qs : 399) * 400;
  }
  const int stg_r = tid >> 3, stg_c = (tid & 7) ^ (stg_r & 7);  // K/V staging

  // ---- main k-tiles: kt = 0..5 (rows kt*64..kt*64+63 < 384 < 400) ----
  for (int kt = 0; kt < 6; ++kt) {
    bf16* Vb = smV[kt & 1];
    // stage K[kt] (64x64) and V^T[kt] (64x64): one uint4 chunk per thread each
    *(uint4*)(smK + tid * 8) =
        *(const uint4*)(Kg + (kt * 64 + stg_r) * 64 + stg_c * 8);
    *(uint4*)(Vb + tid * 8) =
        *(const uint4*)(Vg + stg_r * 400 + kt * 64 + stg_c * 8);
    __syncthreads();

    f32x4 sc[4];
#pragma unroll
    for (int nt = 0; nt < 4; ++nt) sc[nt] = fz;
    __builtin_amdgcn_s_setprio(1);
#pragma unroll
    for (int ks = 0; ks < 2; ++ks)
#pragma unroll
      for (int nt = 0; nt < 4; ++nt) {
        int rk = nt * 16 + lrow;
        bf16x8 bk8 = *(const bf16x8*)(smK + rk * 64 + (((ks * 4 + kg) ^ (rk & 7)) * 8));
        sc[nt] = MFMA(aq[ks], bk8, sc[nt]);
      }
    __builtin_amdgcn_s_setprio(0);

#pragma unroll
    for (int rg = 0; rg < 4; ++rg) {
      const float* mrow = mask + moff[rg];
      float rmax = -1e30f;
#pragma unroll
      for (int nt = 0; nt < 4; ++nt) {
        int ksi = kt * 64 + nt * 16 + lrow;
        float v = fmaf(sc[nt][rg], 0.125f, mrow[ksi]);
        sc[nt][rg] = v;
        rmax = fmaxf(rmax, v);
      }
#pragma unroll
      for (int off = 1; off < 16; off <<= 1)
        rmax = fmaxf(rmax, __shfl_xor(rmax, off, 64));
      float mn = fmaxf(m_run[rg], rmax);
      float alpha = __expf(m_run[rg] - mn);
      m_run[rg] = mn;
      float rsum = 0.f;
#pragma unroll
      for (int nt = 0; nt < 4; ++nt) {
        float p = __expf(sc[nt][rg] - mn);
        sc[nt][rg] = p;
        rsum += p;
      }
      l_part[rg] = l_part[rg] * alpha + rsum;   // lane-local; reduced at end
      o[0][rg] *= alpha; o[1][rg] *= alpha; o[2][rg] *= alpha; o[3][rg] *= alpha;
    }
#pragma unroll
    for (int nt = 0; nt < 4; ++nt)
#pragma unroll
      for (int rg = 0; rg < 4; ++rg) {
        int row = w * 16 + kg * 4 + rg;
        int col = nt * 16 + lrow;
        int ch = (col >> 3) ^ (row & 7);
        smP[row * 64 + ch * 8 + (col & 7)] = (bf16)sc[nt][rg];
      }
    __syncthreads();
    __builtin_amdgcn_s_setprio(1);
#pragma unroll
    for (int ks2 = 0; ks2 < 2; ++ks2) {
      int rp = w * 16 + lrow;
      bf16x8 ap = *(const bf16x8*)(smP + rp * 64 + (((ks2 * 4 + kg) ^ (rp & 7)) * 8));
#pragma unroll
      for (int nt2 = 0; nt2 < 4; ++nt2) {
        int rv = nt2 * 16 + lrow;
        bf16x8 bv8 = *(const bf16x8*)(Vb + rv * 64 + (((ks2 * 4 + kg) ^ (rv & 7)) * 8));
        o[nt2] = MFMA(ap, bv8, o[nt2]);
      }
    }
    __builtin_amdgcn_s_setprio(0);
    // no barrier here: next stage writes smK / smV[other]; PV reads smP / smV[this].
    // smP is protected by the stage->sync of the next iteration.
  }

  // ---- tail k-tile: k = 384..399 (16 wide), buf = 0 (tile 6) ----
  {
    bf16* Vb = smV[0];
    __syncthreads();  // all waves done with smK(5)/smV[1](5); smV[0] dead since kt=4
    if (tid < 128) {
      int r = tid >> 3, cl = tid & 7;
      *(uint4*)(smK + tid * 8) =
          *(const uint4*)(Kg + (384 + r) * 64 + (cl ^ (r & 7)) * 8);
    } else if (tid < 256) {
      int t2 = tid - 128;
      int r = t2 >> 1, ci = t2 & 1;
      *(uint4*)(Vb + r * 64 + ((ci ^ (r & 7)) * 8)) =
          *(const uint4*)(Vg + r * 400 + 384 + ci * 8);
    }
    __syncthreads();

    f32x4 sc0 = fz;
    __builtin_amdgcn_s_setprio(1);
#pragma unroll
    for (int ks = 0; ks < 2; ++ks) {
      bf16x8 bk8 = *(const bf16x8*)(smK + lrow * 64 + (((ks * 4 + kg) ^ (lrow & 7)) * 8));
      sc0 = MFMA(aq[ks], bk8, sc0);
    }
    __builtin_amdgcn_s_setprio(0);

#pragma unroll
    for (int rg = 0; rg < 4; ++rg) {
      float v = fmaf(sc0[rg], 0.125f, mask[moff[rg] + 384 + lrow]);
      float rmax = v;
#pragma unroll
      for (int off = 1; off < 16; off <<= 1)
        rmax = fmaxf(rmax, __shfl_xor(rmax, off, 64));
      float mn = fmaxf(m_run[rg], rmax);
      float alpha = __expf(m_run[rg] - mn);
      m_run[rg] = mn;
      float p = __expf(v - mn);
      sc0[rg] = p;
      l_part[rg] = l_part[rg] * alpha + p;
      o[0][rg] *= alpha; o[1][rg] *= alpha; o[2][rg] *= alpha; o[3][rg] *= alpha;
    }
    // P cols 0..15 = values, cols 16..31 = 0 (V chunks 2,3 are stale-but-finite x 0)
#pragma unroll
    for (int rg = 0; rg < 4; ++rg) {
      int row = w * 16 + kg * 4 + rg;
      int ch0 = (lrow >> 3) ^ (row & 7);
      smP[row * 64 + ch0 * 8 + (lrow & 7)] = (bf16)sc0[rg];
      int ch1 = (2 + (lrow >> 3)) ^ (row & 7);
      smP[row * 64 + ch1 * 8 + (lrow & 7)] = (bf16)0.f;
    }
    __syncthreads();
    __builtin_amdgcn_s_setprio(1);
    {
      int rp = w * 16 + lrow;
      bf16x8 ap = *(const bf16x8*)(smP + rp * 64 + ((kg ^ (rp & 7)) * 8));
#pragma unroll
      for (int nt2 = 0; nt2 < 4; ++nt2) {
        int rv = nt2 * 16 + lrow;
        bf16x8 bv8 = *(const bf16x8*)(Vb + rv * 64 + ((kg ^ (rv & 7)) * 8));
        o[nt2] = MFMA(ap, bv8, o[nt2]);
      }
    }
    __builtin_amdgcn_s_setprio(0);
  }

  const int b = bh >> 4, h = bh & 15;
#pragma unroll
  for (int rg = 0; rg < 4; ++rg) {
    float l = l_part[rg];
#pragma unroll
    for (int off = 1; off < 16; off <<= 1)
      l += __shfl_xor(l, off, 64);
    int qs = qbase + w * 16 + kg * 4 + rg;
    if (qs < 400) {
      float inv = 1.f / l;
#pragma unroll
      for (int nt2 = 0; nt2 < 4; ++nt2) {
        ao[(b * 400 + qs) * 1024 + h * 64 + nt2 * 16 + lrow] =
            (bf16)(o[nt2][rg] * inv);
      }
    }
  }
}

// ---------------- output projection: 512 threads, BK=64, XCD-swizzled ----------------
__global__ __launch_bounds__(512, 4) void gemm_out(
    const bf16* __restrict__ aop, const bf16* __restrict__ Wob,
    const float* __restrict__ bo, const float* __restrict__ gates,
    float* __restrict__ out) {
  const int lid = blockIdx.x;
  const int mI = ((lid >> 6) << 3) + (lid & 7);
  const int nI = (lid >> 3) & 7;
  if (mI >= 100) return;
  __shared__ bf16 sm[16384];
  bf16* smA = sm;
  bf16* smB = sm + 8192;
  const int mbase = mI * 128;
  const int nbase = nI * 128;
  const int tid = threadIdx.x;
  const int lane = tid & 63, w = tid >> 6;
  const int wm = (w >> 1) * 32, wn = (w & 1) * 64;
  const int lrow = lane & 15, kg = lane >> 4;
  const float g = gates[0];
  const f32x4 fz = {0.f, 0.f, 0.f, 0.f};
  f32x4 acc[2][4];
#pragma unroll
  for (int i = 0; i < 2; ++i)
#pragma unroll
    for (int j = 0; j < 4; ++j) acc[i][j] = fz;

  for (int k0 = 0; k0 < 1024; k0 += 64) {
    __syncthreads();
#pragma unroll
    for (int it = 0; it < 2; ++it) {
      int j = it * 512 + tid;
      int r = j >> 3, cl = j & 7;
      g2l16(smA + j * 8, aop + (size_t)(mbase + r) * 1024 + k0 + (cl ^ (r & 7)) * 8);
    }
#pragma unroll
    for (int it = 0; it < 2; ++it) {
      int j = it * 512 + tid;
      int r = j >> 3, cl = j & 7;
      g2l16(smB + j * 8, Wob + (size_t)(nbase + r) * 1024 + k0 + (cl ^ (r & 7)) * 8);
    }
    __syncthreads();
#pragma unroll
    for (int ks = 0; ks < 2; ++ks) {
      bf16x8 af[2], bfr[4];
#pragma unroll
      for (int mt = 0; mt < 2; ++mt) {
        int r = wm + mt * 16 + lrow;
        af[mt] = *(const bf16x8*)(smA + r * 64 + ((ks * 4 + kg) ^ (r & 7)) * 8);
      }
#pragma unroll
      for (int nt = 0; nt < 4; ++nt) {
        int r = wn + nt * 16 + lrow;
        bfr[nt] = *(const bf16x8*)(smB + r * 64 + ((ks * 4 + kg) ^ (r & 7)) * 8);
      }
#pragma unroll
      for (int nt = 0; nt < 4; ++nt)
#pragma unroll
        for (int mt = 0; mt < 2; ++mt)
          acc[mt][nt] = MFMA(af[mt], bfr[nt], acc[mt][nt]);
    }
  }
#pragma unroll
  for (int mt = 0; mt < 2; ++mt)
#pragma unroll
    for (int rg = 0; rg < 4; ++rg) {
      int m = mbase + wm + mt * 16 + kg * 4 + rg;
#pragma unroll
      for (int nt = 0; nt < 4; ++nt) {
        int n = nbase + wn + nt * 16 + lrow;
        out[(size_t)m * 1024 + n] = (acc[mt][nt][rg] + bo[n]) * g;
      }
    }
}

extern "C" void kernel_launch(void* const* d_in, const int* in_sizes, int n_in,
                              void* d_out, int out_size, void* d_ws, size_t ws_size,
                              hipStream_t stream) {
  const float* query = (const float*)d_in[0];
  const float* key   = (const float*)d_in[1];
  const float* value = (const float*)d_in[2];
  const float* mask  = (const float*)d_in[3];
  const float* pe    = (const float*)d_in[4];
  const float* Wq = (const float*)d_in[5];
  const float* bq = (const float*)d_in[6];
  const float* Wk = (const float*)d_in[7];
  const float* bk = (const float*)d_in[8];
  const float* Wv = (const float*)d_in[9];
  const float* bv = (const float*)d_in[10];
  const float* Wp = (const float*)d_in[11];
  const float* bp = (const float*)d_in[12];
  const float* Wo = (const float*)d_in[13];
  const float* bo = (const float*)d_in[14];
  const float* gates = (const float*)d_in[15];
  float* out = (float*)d_out;

  char* base = (char*)d_ws;
  size_t off = 0;
  bf16* wq_b = (bf16*)(base + off); off += 2097152;
  bf16* wk_b = (bf16*)(base + off); off += 2097152;
  bf16* wv_b = (bf16*)(base + off); off += 2097152;
  bf16* wo_b = (bf16*)(base + off); off += 2097152;
  bf16* wp_b = (bf16*)(base + off); off += 2097152;
  bf16* pe_b = (bf16*)(base + off); off += 819200;
  bf16* posq = (bf16*)(base + off); off += 819200;
  bf16* posk = (bf16*)(base + off); off += 819200;
  bf16* posv = (bf16*)(base + off); off += 819200;
  bf16* qb = (bf16*)(base + off); off += 26214400;
  bf16* kb = (bf16*)(base + off); off += 26214400;
  bf16* vt = (bf16*)(base + off); off += 26214400;
  bf16* ao = (bf16*)(base + off); off += 26214400;
  // bf16 X buffers: xq aliases ao (ao written only by attn, after gemm_qkv is
  // done reading xq). xk/xv live in d_out scratch (52.4 MB, fully overwritten
  // by gemm_out at the end — nothing reads stale d_out contents).
  bf16* xq_b = ao;
  bf16* xk_b = (bf16*)d_out;
  bf16* xv_b = (bf16*)d_out + 13107200;
  (void)ws_size; (void)in_sizes; (void)n_in; (void)out_size;

  cvt_all<<<43920, 256, 0, stream>>>(Wq, Wk, Wv, Wo, Wp, pe,
                                     query, key, value,
                                     wq_b, wk_b, wv_b, wo_b, wp_b, pe_b,
                                     xq_b, xk_b, xv_b);
  gemm_pos<<<dim3(8, 4), 256, 0, stream>>>(pe_b, wp_b, bp, bq, bk, bv,
                                           posq, posk, posv);
  gemm_qkv<<<dim3(832, 3), 512, 0, stream>>>(xq_b, xk_b, xv_b,
                                             wq_b, wk_b, wv_b,
                                             posq, posk, posv, qb, kb, vt);
  attn_kernel<<<2048, 512, 0, stream>>>(qb, kb, vt, mask, ao);
  gemm_out<<<832, 512, 0, stream>>>(ao, wo_b, bo, gates, out);
}